// Round 2
// baseline (361.889 us; speedup 1.0000x reference)
//
#include <hip/hip_runtime.h>

// VQ-VAE vector quantizer, MI355X.
// Inputs:  d_in[0] = z_e  f32 (32,64,64,64)  [B,D,H,W]
//          d_in[1] = emb  f32 (512,64)       [K,D]
// Output (flat f32, concat in return order):
//   [0 .. 8388608)   z_q_st  (B,D,H,W)
//   [8388608]        loss_vq
//   [8388609]        perplexity
//   [8388610]        codes_used
//   [8388611]        usage_ratio
//   [8388612]        avg_dist2
//   [8388613 .. +131072) indices (B,H,W) as float
//
// ws layout: [0] f64 sum_sqdiff, [8] f64 sum_mindist, [16] int counts[512],
//            [2064] f32 see[512]

#define NTOK 131072
#define DDIM 64
#define KCB  512
#define HWSZ 4096

__global__ void vq_see_kernel(const float* __restrict__ emb,
                              float* __restrict__ see) {
  int k = blockIdx.x * 64 + threadIdx.x;
  if (k < KCB) {
    const float* e = emb + k * DDIM;
    float s = 0.f;
#pragma unroll
    for (int d = 0; d < DDIM; ++d) s = fmaf(e[d], e[d], s);
    see[k] = s;
  }
}

// 2 tokens per thread: token gid and gid + NTOK/2. Halves scalar-cache
// traffic per FMA (each emb dword feeds 2 FMAs) and gives 8 independent
// accumulator chains for the 4-cyc FMA latency.
__global__ __launch_bounds__(256) void vq_main_kernel(
    const float* __restrict__ z_e, const float* __restrict__ emb,
    const float* __restrict__ see, float* __restrict__ out,
    float* __restrict__ out_idx, int* __restrict__ counts,
    double* __restrict__ sums) {
  __shared__ int hist[KCB];
  __shared__ double sq_s[4];
  __shared__ double md_s[4];

  const int tid = threadIdx.x;
#pragma unroll
  for (int i = tid; i < KCB; i += 256) hist[i] = 0;
  __syncthreads();

  const int gid = blockIdx.x * 256 + tid;

  // z: 2 x 64 fp32 in VGPRs. Lanes contiguous in hw -> coalesced loads.
  float z[2][DDIM];
#pragma unroll
  for (int t = 0; t < 2; ++t) {
    const int tok = gid + t * (NTOK / 2);
    const int b   = tok >> 12;    // /4096
    const int hw  = tok & 4095;
    const float* zp = z_e + (size_t)b * DDIM * HWSZ + hw;
#pragma unroll
    for (int d = 0; d < DDIM; ++d) z[t][d] = zp[(size_t)d * HWSZ];
  }

  // ||z||^2 sequential fp32 (replicates reference rounding scale)
  float szz[2];
#pragma unroll
  for (int t = 0; t < 2; ++t) {
    float s = 0.f;
#pragma unroll
    for (int d = 0; d < DDIM; ++d) s = fmaf(z[t][d], z[t][d], s);
    szz[t] = s;
  }

  float best[2] = {3.4e38f, 3.4e38f};
  int   bidx[2] = {0, 0};

  // k-loop: 4 codes x 2 tokens per iter; emb via wave-uniform scalar loads.
  for (int k = 0; k < KCB; k += 4) {
    float a00 = 0.f, a01 = 0.f, a02 = 0.f, a03 = 0.f;
    float a10 = 0.f, a11 = 0.f, a12 = 0.f, a13 = 0.f;
#pragma unroll
    for (int d = 0; d < DDIM; ++d) {
      const float e0 = emb[(k + 0) * DDIM + d];
      const float e1 = emb[(k + 1) * DDIM + d];
      const float e2 = emb[(k + 2) * DDIM + d];
      const float e3 = emb[(k + 3) * DDIM + d];
      const float z0 = z[0][d];
      const float z1 = z[1][d];
      a00 = fmaf(z0, e0, a00);
      a01 = fmaf(z0, e1, a01);
      a02 = fmaf(z0, e2, a02);
      a03 = fmaf(z0, e3, a03);
      a10 = fmaf(z1, e0, a10);
      a11 = fmaf(z1, e1, a11);
      a12 = fmaf(z1, e2, a12);
      a13 = fmaf(z1, e3, a13);
    }
    const float se0 = see[k + 0];
    const float se1 = see[k + 1];
    const float se2 = see[k + 2];
    const float se3 = see[k + 3];
    // dist = (szz + see_k) - 2*t_k, fp32 op order as in reference
    {
      const float d0 = (szz[0] + se0) - 2.f * a00;
      const float d1 = (szz[0] + se1) - 2.f * a01;
      const float d2 = (szz[0] + se2) - 2.f * a02;
      const float d3 = (szz[0] + se3) - 2.f * a03;
      if (d0 < best[0]) { best[0] = d0; bidx[0] = k + 0; }
      if (d1 < best[0]) { best[0] = d1; bidx[0] = k + 1; }
      if (d2 < best[0]) { best[0] = d2; bidx[0] = k + 2; }
      if (d3 < best[0]) { best[0] = d3; bidx[0] = k + 3; }
    }
    {
      const float d0 = (szz[1] + se0) - 2.f * a10;
      const float d1 = (szz[1] + se1) - 2.f * a11;
      const float d2 = (szz[1] + se2) - 2.f * a12;
      const float d3 = (szz[1] + se3) - 2.f * a13;
      if (d0 < best[1]) { best[1] = d0; bidx[1] = k + 0; }
      if (d1 < best[1]) { best[1] = d1; bidx[1] = k + 1; }
      if (d2 < best[1]) { best[1] = d2; bidx[1] = k + 2; }
      if (d3 < best[1]) { best[1] = d3; bidx[1] = k + 3; }
    }
  }

  double sq = 0.0;
  double md = 0.0;

#pragma unroll
  for (int t = 0; t < 2; ++t) {
    atomicAdd(&hist[bidx[t]], 1);

    const int tok = gid + t * (NTOK / 2);
    const int b   = tok >> 12;
    const int hw  = tok & 4095;

    // gather z_q row (float4, L2-resident), write z_q_st, accumulate sq-diff
    const float4* eq = reinterpret_cast<const float4*>(emb + bidx[t] * DDIM);
    float* op = out + (size_t)b * DDIM * HWSZ + hw;
#pragma unroll
    for (int d4 = 0; d4 < 16; ++d4) {
      const float4 q = eq[d4];
      const float zq[4] = {q.x, q.y, q.z, q.w};
#pragma unroll
      for (int c = 0; c < 4; ++c) {
        const int d = 4 * d4 + c;
        const float df  = zq[c] - z[t][d];     // fp32 round
        const float val = z[t][d] + df;        // z_e + (z_q - z_e), fp32 round
        op[(size_t)d * HWSZ] = val;
        sq = fma((double)df, (double)df, sq);
      }
    }

    out_idx[tok] = (float)bidx[t];
    md += (double)best[t];
  }

  // block-reduce sq and min-dist (f64), one atomic pair per block
#pragma unroll
  for (int off = 32; off > 0; off >>= 1) {
    sq += __shfl_down(sq, off);
    md += __shfl_down(md, off);
  }
  const int wave = tid >> 6;
  if ((tid & 63) == 0) { sq_s[wave] = sq; md_s[wave] = md; }
  __syncthreads();
  if (tid == 0) {
    double tsq = sq_s[0] + sq_s[1] + sq_s[2] + sq_s[3];
    double tmd = md_s[0] + md_s[1] + md_s[2] + md_s[3];
    unsafeAtomicAdd(&sums[0], tsq);
    unsafeAtomicAdd(&sums[1], tmd);
  }

  // flush histogram
  for (int i = tid; i < KCB; i += 256) {
    int h = hist[i];
    if (h) atomicAdd(&counts[i], h);
  }
}

__global__ void vq_final_kernel(const int* __restrict__ counts,
                                const double* __restrict__ sums,
                                float* __restrict__ scal) {
  __shared__ double ent_s[8];
  __shared__ int    used_s[8];
  const int tid = threadIdx.x;  // 512 threads
  const int c = counts[tid];
  const double p = (double)c / 131072.0;
  double e = (c > 0) ? (-p * log(p)) : 0.0;
  int u = (c > 0) ? 1 : 0;
#pragma unroll
  for (int off = 32; off > 0; off >>= 1) {
    e += __shfl_down(e, off);
    u += __shfl_down(u, off);
  }
  if ((tid & 63) == 0) { ent_s[tid >> 6] = e; used_s[tid >> 6] = u; }
  __syncthreads();
  if (tid == 0) {
    double ent = 0.0; int used = 0;
#pragma unroll
    for (int w = 0; w < 8; ++w) { ent += ent_s[w]; used += used_s[w]; }
    const double mse = sums[0] / 8388608.0;        // mean over B*D*H*W
    scal[0] = (float)(mse * 64.0 * 1.25);          // loss_vq = (1+beta)*mse*D
    scal[1] = (float)exp(ent);                     // perplexity
    scal[2] = (float)used;                         // codes_used
    scal[3] = (float)used / 512.f;                 // usage_ratio
    scal[4] = (float)(sums[1] / 131072.0);         // avg_dist2
  }
}

extern "C" void kernel_launch(void* const* d_in, const int* in_sizes, int n_in,
                              void* d_out, int out_size, void* d_ws,
                              size_t ws_size, hipStream_t stream) {
  const float* z_e = (const float*)d_in[0];
  const float* emb = (const float*)d_in[1];
  float* out = (float*)d_out;

  double* sums  = (double*)d_ws;
  int*   counts = (int*)((char*)d_ws + 16);
  float* see    = (float*)((char*)d_ws + 16 + 2048);

  hipMemsetAsync(d_ws, 0, 16 + 2048, stream);
  vq_see_kernel<<<8, 64, 0, stream>>>(emb, see);
  vq_main_kernel<<<256, 256, 0, stream>>>(z_e, emb, see, out,
                                          out + 8388613, counts, sums);
  vq_final_kernel<<<1, 512, 0, stream>>>(counts, sums, out + 8388608);
}

// Round 3
// 231.584 us; speedup vs baseline: 1.5627x; 1.5627x over previous
//
#include <hip/hip_runtime.h>

// VQ-VAE vector quantizer, MI355X — v3: K-split x4 + LDS-broadcast emb.
// Inputs:  d_in[0] = z_e  f32 (32,64,64,64)  [B,D,H,W]
//          d_in[1] = emb  f32 (512,64)       [K,D]
// Output (flat f32): [0..8388608) z_q_st | [8388608..8388613) scalars
//                    (loss_vq, perplexity, codes_used, usage_ratio, avg_dist2)
//                    | [8388613..+131072) indices as float
// ws: [0..16) f64 sums | [16..2064) int counts[512] | [2064..4112) f32 see[512]
//     | [4608..4608+4MiB) float2 pairs[4][131072] {best, idx-bits}

#define NTOK 131072
#define DDIM 64
#define KCB  512
#define KQ   128      // codes per k-quarter
#define HWSZ 4096

__global__ void vq_see_kernel(const float* __restrict__ emb,
                              float* __restrict__ see) {
  int k = blockIdx.x * 64 + threadIdx.x;
  if (k < KCB) {
    const float* e = emb + k * DDIM;
    float s = 0.f;
#pragma unroll
    for (int d = 0; d < DDIM; ++d) s = fmaf(e[d], e[d], s);
    see[k] = s;
  }
}

// Search: 1024 blocks x 256 thr. block = (token-group tb) x (k-quarter kq).
// Each thread: 2 tokens (z in VGPRs), 128 codes from LDS via uniform
// ds_read_b128 broadcasts. Writes per-token {best, idx} pairs.
__global__ __launch_bounds__(256, 2) void vq_search_kernel(
    const float* __restrict__ z_e, const float* __restrict__ emb,
    const float* __restrict__ see, float2* __restrict__ pairs) {
  __shared__ float4 ldsE[KQ][16];
  __shared__ float  ldsS[KQ];

  const int tid = threadIdx.x;
  const int kq  = blockIdx.x & 3;
  const int tb  = blockIdx.x >> 2;          // 0..255 token groups of 512
  const int kqbase = kq * KQ;

  // stage the 32KB code quarter + see quarter into LDS (coalesced)
  {
    const float4* src = reinterpret_cast<const float4*>(emb) + kqbase * 16;
    float4* dst = &ldsE[0][0];
#pragma unroll
    for (int v = tid; v < KQ * 16; v += 256) dst[v] = src[v];
    if (tid < KQ) ldsS[tid] = see[kqbase + tid];
  }
  __syncthreads();

  // two tokens per thread, lanes contiguous in hw -> coalesced loads
  float z[2][DDIM];
  float szz[2];
#pragma unroll
  for (int t = 0; t < 2; ++t) {
    const int tok = tb * 512 + t * 256 + tid;
    const int b   = tok >> 12;
    const int hw  = tok & 4095;
    const float* zp = z_e + (size_t)b * DDIM * HWSZ + hw;
#pragma unroll
    for (int d = 0; d < DDIM; ++d) z[t][d] = zp[(size_t)d * HWSZ];
    float s = 0.f;
#pragma unroll
    for (int d = 0; d < DDIM; ++d) s = fmaf(z[t][d], z[t][d], s);
    szz[t] = s;
  }

  float best[2] = {3.4e38f, 3.4e38f};
  int   bidx[2] = {kqbase, kqbase};

  for (int kk = 0; kk < KQ; kk += 2) {
    float a00 = 0.f, a01 = 0.f, a10 = 0.f, a11 = 0.f;
    const float4* e0p = ldsE[kk + 0];
    const float4* e1p = ldsE[kk + 1];
#pragma unroll
    for (int dv = 0; dv < 16; ++dv) {
      const float4 e0 = e0p[dv];     // uniform addr -> LDS broadcast
      const float4 e1 = e1p[dv];
      const float z00 = z[0][4 * dv + 0], z01 = z[0][4 * dv + 1];
      const float z02 = z[0][4 * dv + 2], z03 = z[0][4 * dv + 3];
      const float z10 = z[1][4 * dv + 0], z11 = z[1][4 * dv + 1];
      const float z12 = z[1][4 * dv + 2], z13 = z[1][4 * dv + 3];
      a00 = fmaf(z00, e0.x, a00); a00 = fmaf(z01, e0.y, a00);
      a00 = fmaf(z02, e0.z, a00); a00 = fmaf(z03, e0.w, a00);
      a01 = fmaf(z00, e1.x, a01); a01 = fmaf(z01, e1.y, a01);
      a01 = fmaf(z02, e1.z, a01); a01 = fmaf(z03, e1.w, a01);
      a10 = fmaf(z10, e0.x, a10); a10 = fmaf(z11, e0.y, a10);
      a10 = fmaf(z12, e0.z, a10); a10 = fmaf(z13, e0.w, a10);
      a11 = fmaf(z10, e1.x, a11); a11 = fmaf(z11, e1.y, a11);
      a11 = fmaf(z12, e1.z, a11); a11 = fmaf(z13, e1.w, a11);
    }
    const float se0 = ldsS[kk + 0];
    const float se1 = ldsS[kk + 1];
    const int   kg  = kqbase + kk;
    float d;
    // dist = (szz + see_k) - 2*t_k  (exact fp32 order, matches reference)
    d = (szz[0] + se0) - 2.f * a00; if (d < best[0]) { best[0] = d; bidx[0] = kg; }
    d = (szz[0] + se1) - 2.f * a01; if (d < best[0]) { best[0] = d; bidx[0] = kg + 1; }
    d = (szz[1] + se0) - 2.f * a10; if (d < best[1]) { best[1] = d; bidx[1] = kg; }
    d = (szz[1] + se1) - 2.f * a11; if (d < best[1]) { best[1] = d; bidx[1] = kg + 1; }
  }

#pragma unroll
  for (int t = 0; t < 2; ++t) {
    const int tok = tb * 512 + t * 256 + tid;
    float2 p;
    p.x = best[t];
    p.y = __int_as_float(bidx[t]);
    pairs[(size_t)kq * NTOK + tok] = p;
  }
}

// Combine quarters + full epilogue. 512 blocks x 256 thr, 1 token/thread.
__global__ __launch_bounds__(256) void vq_epilogue_kernel(
    const float* __restrict__ z_e, const float* __restrict__ emb,
    const float2* __restrict__ pairs, float* __restrict__ out,
    float* __restrict__ out_idx, int* __restrict__ counts,
    double* __restrict__ sums) {
  __shared__ int hist[KCB];
  __shared__ double sq_s[4];
  __shared__ double md_s[4];

  const int tid = threadIdx.x;
#pragma unroll
  for (int i = tid; i < KCB; i += 256) hist[i] = 0;
  __syncthreads();

  const int tok = blockIdx.x * 256 + tid;
  const int b   = tok >> 12;
  const int hw  = tok & 4095;

  // combine in ascending quarter order, strict < : exact first-occurrence
  float best = 3.4e38f;
  int   bidx = 0;
#pragma unroll
  for (int q = 0; q < 4; ++q) {
    const float2 p = pairs[(size_t)q * NTOK + tok];
    if (p.x < best) { best = p.x; bidx = __float_as_int(p.y); }
  }

  atomicAdd(&hist[bidx], 1);

  const float* zp = z_e + (size_t)b * DDIM * HWSZ + hw;
  float* op = out + (size_t)b * DDIM * HWSZ + hw;
  const float4* eq = reinterpret_cast<const float4*>(emb + bidx * DDIM);

  double sq = 0.0;
#pragma unroll
  for (int d4 = 0; d4 < 16; ++d4) {
    const float4 q = eq[d4];
    const float zq[4] = {q.x, q.y, q.z, q.w};
#pragma unroll
    for (int c = 0; c < 4; ++c) {
      const int d = 4 * d4 + c;
      const float ze  = zp[(size_t)d * HWSZ];
      const float df  = zq[c] - ze;          // fp32 round
      const float val = ze + df;             // z_e + (z_q - z_e), fp32 round
      op[(size_t)d * HWSZ] = val;
      sq = fma((double)df, (double)df, sq);
    }
  }

  out_idx[tok] = (float)bidx;

  double md = (double)best;
#pragma unroll
  for (int off = 32; off > 0; off >>= 1) {
    sq += __shfl_down(sq, off);
    md += __shfl_down(md, off);
  }
  const int wave = tid >> 6;
  if ((tid & 63) == 0) { sq_s[wave] = sq; md_s[wave] = md; }
  __syncthreads();
  if (tid == 0) {
    double tsq = sq_s[0] + sq_s[1] + sq_s[2] + sq_s[3];
    double tmd = md_s[0] + md_s[1] + md_s[2] + md_s[3];
    unsafeAtomicAdd(&sums[0], tsq);
    unsafeAtomicAdd(&sums[1], tmd);
  }

  for (int i = tid; i < KCB; i += 256) {
    const int h = hist[i];
    if (h) atomicAdd(&counts[i], h);
  }
}

__global__ void vq_final_kernel(const int* __restrict__ counts,
                                const double* __restrict__ sums,
                                float* __restrict__ scal) {
  __shared__ double ent_s[8];
  __shared__ int    used_s[8];
  const int tid = threadIdx.x;  // 512 threads
  const int c = counts[tid];
  const double p = (double)c / 131072.0;
  double e = (c > 0) ? (-p * log(p)) : 0.0;
  int u = (c > 0) ? 1 : 0;
#pragma unroll
  for (int off = 32; off > 0; off >>= 1) {
    e += __shfl_down(e, off);
    u += __shfl_down(u, off);
  }
  if ((tid & 63) == 0) { ent_s[tid >> 6] = e; used_s[tid >> 6] = u; }
  __syncthreads();
  if (tid == 0) {
    double ent = 0.0; int used = 0;
#pragma unroll
    for (int w = 0; w < 8; ++w) { ent += ent_s[w]; used += used_s[w]; }
    const double mse = sums[0] / 8388608.0;        // mean over B*D*H*W
    scal[0] = (float)(mse * 64.0 * 1.25);          // loss_vq = (1+beta)*mse*D
    scal[1] = (float)exp(ent);                     // perplexity
    scal[2] = (float)used;                         // codes_used
    scal[3] = (float)used / 512.f;                 // usage_ratio
    scal[4] = (float)(sums[1] / 131072.0);         // avg_dist2
  }
}

extern "C" void kernel_launch(void* const* d_in, const int* in_sizes, int n_in,
                              void* d_out, int out_size, void* d_ws,
                              size_t ws_size, hipStream_t stream) {
  const float* z_e = (const float*)d_in[0];
  const float* emb = (const float*)d_in[1];
  float* out = (float*)d_out;

  double* sums   = (double*)d_ws;
  int*    counts = (int*)((char*)d_ws + 16);
  float*  see    = (float*)((char*)d_ws + 2064);
  float2* pairs  = (float2*)((char*)d_ws + 4608);

  hipMemsetAsync(d_ws, 0, 2064, stream);
  vq_see_kernel<<<8, 64, 0, stream>>>(emb, see);
  vq_search_kernel<<<1024, 256, 0, stream>>>(z_e, emb, see, pairs);
  vq_epilogue_kernel<<<512, 256, 0, stream>>>(z_e, emb, pairs, out,
                                              out + 8388613, counts, sums);
  vq_final_kernel<<<1, 512, 0, stream>>>(counts, sums, out + 8388608);
}